// Round 8
// baseline (282.640 us; speedup 1.0000x reference)
//
#include <hip/hip_runtime.h>
#include <math.h>

#define NPX 4096          // 64*64 low-res pixels per batch
#define H2 128
#define W2 128
#define PP 66             // padded mid plane 66x66, interior 1..64
#define XPP 68            // padded X plane 68x68, interior 2..65

// K1: 1x1 conv (256->64) + BN + ReLU into padded mid_p[b][co][66][66].
// grid (128 = 2b x 64 rows, 16 co-groups of 4), block 256 = 4 ci-quarter waves.
// co-group-0 blocks additionally copy their X rows into padded Xp (for K3).
__global__ __launch_bounds__(256) void k1_conv1x1(
    const float* __restrict__ X, const float* __restrict__ w,
    const float* __restrict__ g, const float* __restrict__ bt,
    const float* __restrict__ m, const float* __restrict__ var,
    float* __restrict__ mid_p, float* __restrict__ Xp)
{
    __shared__ float red[3 * 4 * 64];   // 3 KB
    int tid = threadIdx.x;
    int x = tid & 63;
    int ciq = __builtin_amdgcn_readfirstlane(tid >> 6);   // 0..3
    int bx = blockIdx.x;
    int bb = bx >> 6, y = bx & 63;
    int co0 = blockIdx.y * 4;
    int ci0 = ciq * 64;
    bool dopad = (blockIdx.y == 0);     // block-uniform

    const float* xp = X + ((size_t)(bb * 256 + ci0)) * NPX + y * 64 + x;
    const float* wp = w + (size_t)co0 * 256 + ci0;   // uniform -> s_load
    float* xpad = Xp + ((size_t)(bb * 256 + ci0) * XPP + (y + 2)) * XPP + (x + 2);

    float acc[4] = {0.f, 0.f, 0.f, 0.f};

    #pragma unroll 8
    for (int ci = 0; ci < 64; ++ci) {
        float xv = xp[(size_t)ci * NPX];
        if (dopad) xpad[(size_t)ci * (XPP * XPP)] = xv;
        #pragma unroll
        for (int j = 0; j < 4; ++j)
            acc[j] += xv * wp[j * 256 + ci];
    }

    if (ciq > 0) {
        #pragma unroll
        for (int j = 0; j < 4; ++j)
            red[((ciq - 1) * 4 + j) * 64 + x] = acc[j];
    }
    __syncthreads();
    if (ciq == 0) {
        #pragma unroll
        for (int j = 0; j < 4; ++j) {
            float a = acc[j] + red[(0 * 4 + j) * 64 + x]
                             + red[(1 * 4 + j) * 64 + x]
                             + red[(2 * 4 + j) * 64 + x];
            int co = co0 + j;
            float inv = g[co] * rsqrtf(var[co] + 1e-5f);
            a = fmaxf(a * inv + (bt[co] - m[co] * inv), 0.f);
            mid_p[((size_t)(bb * 64 + co) * PP + (y + 1)) * PP + (x + 1)] = a;
        }
    }
}

// K2 (fused conv3x3 + BN + clamp + pow + softmax): grid 128 = 2b x 64 rows,
// block 256 = 4 waves; wave = sub-position s, lane = x. Thread accumulates its
// 25 taps (co = 4k+s) over the FULL 64-ci loop (225 FMA per 9 loads -> per-thread
// ILP hides latency), then does the softmax in-register and writes wn directly.
// No LDS, no barriers, no enc buffer.
__global__ __launch_bounds__(256) void k2_fused(
    const float* __restrict__ mid_p, const float* __restrict__ ew,
    const float* __restrict__ g, const float* __restrict__ bt,
    const float* __restrict__ m, const float* __restrict__ var,
    const float* __restrict__ power_p,
    float* __restrict__ wn)
{
    int tid = threadIdx.x;
    int x = tid & 63;
    int s = __builtin_amdgcn_readfirstlane(tid >> 6);   // 0..3
    int bx = blockIdx.x;
    int bb = bx >> 6, y = bx & 63;

    const float* wb = ew + (size_t)s * 576;     // + k*2304 + ci*9  (uniform)
    const float* P0 = mid_p + (((size_t)bb * 64) * PP + y) * PP + x;

    float acc[25];
    #pragma unroll
    for (int k = 0; k < 25; ++k) acc[k] = 0.f;

    // software-pipelined 9-tap window loads
    float v0 = P0[0],      v1 = P0[1],          v2 = P0[2];
    float v3 = P0[PP],     v4 = P0[PP + 1],     v5 = P0[PP + 2];
    float v6 = P0[2 * PP], v7 = P0[2 * PP + 1], v8 = P0[2 * PP + 2];

    for (int ci = 0; ci < 64; ++ci) {
        int cn = (ci < 63) ? ci + 1 : 63;
        const float* Pn = P0 + (size_t)cn * (PP * PP);
        float n0 = Pn[0],      n1 = Pn[1],          n2 = Pn[2];
        float n3 = Pn[PP],     n4 = Pn[PP + 1],     n5 = Pn[PP + 2];
        float n6 = Pn[2 * PP], n7 = Pn[2 * PP + 1], n8 = Pn[2 * PP + 2];

        const float* wp = wb + ci * 9;          // uniform -> s_load
        #pragma unroll
        for (int k = 0; k < 25; ++k) {
            const float* wj = wp + k * 2304;    // co = 4k+s
            acc[k] += v0 * wj[0] + v1 * wj[1] + v2 * wj[2]
                    + v3 * wj[3] + v4 * wj[4] + v5 * wj[5]
                    + v6 * wj[6] + v7 * wj[7] + v8 * wj[8];
        }
        v0 = n0; v1 = n1; v2 = n2; v3 = n3; v4 = n4;
        v5 = n5; v6 = n6; v7 = n7; v8 = n8;
    }

    // epilogue: BN + clamp + pow + softmax over the 25 taps
    float pw = fmaxf(power_p[0], 1e-5f);
    float mx = -1e30f;
    #pragma unroll
    for (int k = 0; k < 25; ++k) {
        int co = 4 * k + s;
        float inv = g[co] * rsqrtf(var[co] + 1e-5f);
        float e = acc[k] * inv + (bt[co] - m[co] * inv);
        e = fmaxf(e, 1e-5f);
        float t = exp2f(pw * log2f(e));
        acc[k] = t;
        mx = fmaxf(mx, t);
    }
    float sum = 0.f;
    #pragma unroll
    for (int k = 0; k < 25; ++k) {
        float e = expf(acc[k] - mx);
        acc[k] = e;
        sum += e;
    }
    float r = 1.0f / sum;
    float* op = wn + ((size_t)bb * 100 + s * 25) * NPX + y * 64 + x;
    #pragma unroll
    for (int k = 0; k < 25; ++k)
        op[(size_t)k * NPX] = acc[k] * r;
}

// K3: reassembly, LDS-free. grid (32 = 2b x 8... actually 2b x 16 row-quads,
// 16 ch-groups), block 256 = 4 rows x 64 px. Thread = one low-res px: holds all
// 100 weights in VGPRs (4-way s-sharing of the X window), loops 16 ch reading
// the 5x5 window directly from padded Xp (L1-resident per block), stores the
// 2x2 out block as two coalesced float2.
__global__ __launch_bounds__(256, 2) void k3_carafe(
    const float* __restrict__ Xp, const float* __restrict__ wn,
    float* __restrict__ out)
{
    int tid = threadIdx.x;
    int bx = blockIdx.x;
    int bb = bx >> 4;
    int rg = bx & 15;
    int y = rg * 4 + (tid >> 6);
    int px = tid & 63;
    int c0 = blockIdx.y * 16;

    float wv[100];
    const float* wsrc = wn + ((size_t)bb * 100) * NPX + y * 64 + px;
    #pragma unroll
    for (int j = 0; j < 100; ++j)
        wv[j] = wsrc[(size_t)j * NPX];

    const float* xb = Xp + ((size_t)(bb * 256 + c0) * XPP + y) * XPP + px;
    float* ob = out + ((size_t)(bb * 256 + c0) * H2 + 2 * y) * W2 + 2 * px;

    for (int ch = 0; ch < 16; ++ch) {
        const float* P = xb + (size_t)ch * (XPP * XPP);
        float xv[25];
        #pragma unroll
        for (int ki = 0; ki < 5; ++ki)
            #pragma unroll
            for (int kj = 0; kj < 5; ++kj)
                xv[ki * 5 + kj] = P[ki * XPP + kj];
        float a0 = 0.f, a1 = 0.f, a2 = 0.f, a3 = 0.f;
        #pragma unroll
        for (int k = 0; k < 25; ++k) {
            a0 += wv[k]      * xv[k];
            a1 += wv[25 + k] * xv[k];
            a2 += wv[50 + k] * xv[k];
            a3 += wv[75 + k] * xv[k];
        }
        float* o = ob + (size_t)ch * (H2 * W2);
        *(float2*)o        = make_float2(a0, a1);
        *(float2*)(o + W2) = make_float2(a2, a3);
    }
}

extern "C" void kernel_launch(void* const* d_in, const int* in_sizes, int n_in,
                              void* d_out, int out_size, void* d_ws, size_t ws_size,
                              hipStream_t stream)
{
    const float* X  = (const float*)d_in[0];
    const float* cw = (const float*)d_in[1];
    const float* cg = (const float*)d_in[2];
    const float* cb = (const float*)d_in[3];
    const float* cm = (const float*)d_in[4];
    const float* cv = (const float*)d_in[5];
    const float* ew = (const float*)d_in[6];
    const float* eg = (const float*)d_in[7];
    const float* eb = (const float*)d_in[8];
    const float* em = (const float*)d_in[9];
    const float* ev = (const float*)d_in[10];
    const float* pp = (const float*)d_in[11];
    float* out = (float*)d_out;

    float* ws   = (float*)d_ws;
    float* midp = ws;                           // 2*64*66*66  = 557,568 floats
    float* Xp   = ws + 557568;                  // 2*256*68*68 = 2,367,488 floats
    float* wn   = ws + 557568 + 2367488;        // 2*100*4096  = 819,200 floats

    // zero midp + Xp (borders must be 0; interiors overwritten by k1)
    hipMemsetAsync(ws, 0, (557568 + 2367488) * sizeof(float), stream);
    k1_conv1x1<<<dim3(128, 16), 256, 0, stream>>>(X, cw, cg, cb, cm, cv, midp, Xp);
    k2_fused<<<dim3(128), 256, 0, stream>>>(midp, ew, eg, eb, em, ev, pp, wn);
    k3_carafe<<<dim3(32, 16), 256, 0, stream>>>(Xp, wn, out);
}

// Round 9
// 179.256 us; speedup vs baseline: 1.5767x; 1.5767x over previous
//
#include <hip/hip_runtime.h>
#include <math.h>

#define NPX 4096          // 64*64 low-res pixels per batch
#define H2 128
#define W2 128
#define PP 66             // padded mid plane 66x66, interior 1..64
#define XPP 68            // padded X plane 68x68, interior 2..65

// K1: 1x1 conv (256->64) + BN + ReLU into padded mid_p. Weights via LDS
// broadcast (NOT s_load). grid (64 = 2b x 32 row-pairs, 8 co-groups of 8),
// block 256 = 4 ci-quarter waves; thread = lane x, 2 rows, 8 co (acc 16).
// co-group-0 blocks also copy their X rows into padded Xp (for K3).
__global__ __launch_bounds__(256) void k1_conv1x1(
    const float* __restrict__ X, const float* __restrict__ w,
    const float* __restrict__ g, const float* __restrict__ bt,
    const float* __restrict__ m, const float* __restrict__ var,
    float* __restrict__ mid_p, float* __restrict__ Xp)
{
    __shared__ float wl[256 * 8];     // [ci][j] 8 KB
    __shared__ float red[3 * 16 * 64]; // 12 KB
    int tid = threadIdx.x;
    int x = tid & 63;
    int ciq = __builtin_amdgcn_readfirstlane(tid >> 6);   // 0..3
    int bx = blockIdx.x;
    int bb = bx >> 5, y0 = (bx & 31) * 2;
    int co0 = blockIdx.y * 8;
    int ci0 = ciq * 64;
    bool dopad = (blockIdx.y == 0);

    for (int idx = tid; idx < 2048; idx += 256) {
        int ci = idx >> 3, j = idx & 7;
        wl[idx] = w[(size_t)(co0 + j) * 256 + ci];
    }
    __syncthreads();

    float acc[2][8];
    #pragma unroll
    for (int r = 0; r < 2; ++r)
        #pragma unroll
        for (int j = 0; j < 8; ++j) acc[r][j] = 0.f;

    const float* xp = X + ((size_t)(bb * 256 + ci0)) * NPX + y0 * 64 + x;
    float* xpad = Xp + ((size_t)(bb * 256 + ci0) * XPP + (y0 + 2)) * XPP + (x + 2);

    for (int ci = 0; ci < 64; ++ci) {
        float x0 = xp[(size_t)ci * NPX];
        float x1 = xp[(size_t)ci * NPX + 64];
        if (dopad) {
            xpad[(size_t)ci * (XPP * XPP)] = x0;
            xpad[(size_t)ci * (XPP * XPP) + XPP] = x1;
        }
        const float4* wq = (const float4*)&wl[(ci0 + ci) * 8];
        float4 wa = wq[0], wb = wq[1];
        acc[0][0] += x0 * wa.x; acc[0][1] += x0 * wa.y; acc[0][2] += x0 * wa.z; acc[0][3] += x0 * wa.w;
        acc[0][4] += x0 * wb.x; acc[0][5] += x0 * wb.y; acc[0][6] += x0 * wb.z; acc[0][7] += x0 * wb.w;
        acc[1][0] += x1 * wa.x; acc[1][1] += x1 * wa.y; acc[1][2] += x1 * wa.z; acc[1][3] += x1 * wa.w;
        acc[1][4] += x1 * wb.x; acc[1][5] += x1 * wb.y; acc[1][6] += x1 * wb.z; acc[1][7] += x1 * wb.w;
    }

    if (ciq > 0) {
        #pragma unroll
        for (int r = 0; r < 2; ++r)
            #pragma unroll
            for (int j = 0; j < 8; ++j)
                red[((ciq - 1) * 16 + r * 8 + j) * 64 + x] = acc[r][j];
    }
    __syncthreads();
    if (ciq == 0) {
        #pragma unroll
        for (int r = 0; r < 2; ++r)
            #pragma unroll
            for (int j = 0; j < 8; ++j) {
                float a = acc[r][j] + red[(0 * 16 + r * 8 + j) * 64 + x]
                                    + red[(1 * 16 + r * 8 + j) * 64 + x]
                                    + red[(2 * 16 + r * 8 + j) * 64 + x];
                int co = co0 + j;
                float inv = g[co] * rsqrtf(var[co] + 1e-5f);
                a = fmaxf(a * inv + (bt[co] - m[co] * inv), 0.f);
                mid_p[((size_t)(bb * 64 + co) * PP + (y0 + r + 1)) * PP + (x + 1)] = a;
            }
    }
}

// K2a: 3x3 conv (64->100). Weights (10co x 64ci x 9 = 23 KB) staged once in
// LDS, read as same-address broadcasts. grid (64 = 2b x 32 row-pairs,
// 10 co-groups of 10) = 640 blocks; block 256 = 4 ci-quarter waves; thread =
// lane x, 2 rows, 10 co (acc 20), 12-load window from padded mid_p (L2).
__global__ __launch_bounds__(256) void k2a_conv3x3(
    const float* __restrict__ mid_p, const float* __restrict__ ew,
    float* __restrict__ enc)
{
    __shared__ float wl[5760];          // [ci][j][k] 23 KB
    __shared__ float red[3 * 20 * 64];  // 15 KB
    int tid = threadIdx.x;
    int x = tid & 63;
    int ciq = __builtin_amdgcn_readfirstlane(tid >> 6);   // 0..3
    int bx = blockIdx.x;
    int bb = bx >> 5, y0 = (bx & 31) * 2;
    int co0 = blockIdx.y * 10;

    for (int idx = tid; idx < 5760; idx += 256) {
        int j = idx / 576;
        int rem = idx - j * 576;        // ci*9 + k
        int ci = rem / 9, k = rem - ci * 9;
        wl[ci * 90 + j * 9 + k] = ew[(size_t)(co0 + j) * 576 + rem];
    }
    __syncthreads();

    float acc[2][10];
    #pragma unroll
    for (int r = 0; r < 2; ++r)
        #pragma unroll
        for (int j = 0; j < 10; ++j) acc[r][j] = 0.f;

    const float* P = mid_p + (((size_t)(bb * 64 + ciq * 16)) * PP + y0) * PP + x;

    for (int ci = 0; ci < 16; ++ci) {
        const float* P0 = P + (size_t)ci * (PP * PP);
        float v[4][3];
        #pragma unroll
        for (int r = 0; r < 4; ++r) {
            v[r][0] = P0[r * PP];
            v[r][1] = P0[r * PP + 1];
            v[r][2] = P0[r * PP + 2];
        }
        const float* wq = &wl[(ciq * 16 + ci) * 90];
        #pragma unroll
        for (int j = 0; j < 10; ++j) {
            float w0 = wq[j * 9 + 0], w1 = wq[j * 9 + 1], w2 = wq[j * 9 + 2];
            float w3 = wq[j * 9 + 3], w4 = wq[j * 9 + 4], w5 = wq[j * 9 + 5];
            float w6 = wq[j * 9 + 6], w7 = wq[j * 9 + 7], w8 = wq[j * 9 + 8];
            acc[0][j] += v[0][0] * w0 + v[0][1] * w1 + v[0][2] * w2
                       + v[1][0] * w3 + v[1][1] * w4 + v[1][2] * w5
                       + v[2][0] * w6 + v[2][1] * w7 + v[2][2] * w8;
            acc[1][j] += v[1][0] * w0 + v[1][1] * w1 + v[1][2] * w2
                       + v[2][0] * w3 + v[2][1] * w4 + v[2][2] * w5
                       + v[3][0] * w6 + v[3][1] * w7 + v[3][2] * w8;
        }
    }

    if (ciq > 0) {
        #pragma unroll
        for (int r = 0; r < 2; ++r)
            #pragma unroll
            for (int j = 0; j < 10; ++j)
                red[((ciq - 1) * 20 + r * 10 + j) * 64 + x] = acc[r][j];
    }
    __syncthreads();
    if (ciq == 0) {
        #pragma unroll
        for (int r = 0; r < 2; ++r)
            #pragma unroll
            for (int j = 0; j < 10; ++j) {
                float a = acc[r][j] + red[(0 * 20 + r * 10 + j) * 64 + x]
                                    + red[(1 * 20 + r * 10 + j) * 64 + x]
                                    + red[(2 * 20 + r * 10 + j) * 64 + x];
                enc[((size_t)bb * 100 + co0 + j) * NPX + (y0 + r) * 64 + x] = a;
            }
    }
}

// K2b: BN + clamp + pow + softmax over 25 taps. wn layout [b][s*25+k][px].
__global__ __launch_bounds__(64) void k2b_softmax(
    const float* __restrict__ enc,
    const float* __restrict__ g, const float* __restrict__ bt,
    const float* __restrict__ m, const float* __restrict__ var,
    const float* __restrict__ power_p,
    float* __restrict__ wn)
{
    int s = blockIdx.x & 3;
    int p = (blockIdx.x >> 2) * 64 + threadIdx.x;
    int bb = p >> 12, sp = p & (NPX - 1);
    float pw = fmaxf(power_p[0], 1e-5f);
    float tv[25];
    float mx = -1e30f;
    #pragma unroll
    for (int k = 0; k < 25; ++k) {
        int co = 4 * k + s;
        float inv = g[co] * rsqrtf(var[co] + 1e-5f);
        float e = enc[((size_t)bb * 100 + co) * NPX + sp] * inv + (bt[co] - m[co] * inv);
        e = fmaxf(e, 1e-5f);
        float xq = exp2f(pw * log2f(e));
        tv[k] = xq;
        mx = fmaxf(mx, xq);
    }
    float sum = 0.f;
    #pragma unroll
    for (int k = 0; k < 25; ++k) {
        float e = expf(tv[k] - mx);
        tv[k] = e;
        sum += e;
    }
    float r = 1.0f / sum;
    #pragma unroll
    for (int k = 0; k < 25; ++k)
        wn[((size_t)bb * 100 + s * 25 + k) * NPX + sp] = tv[k] * r;
}

// K3: reassembly, LDS-free. grid (32 = 2b x 16 row-quads, 16 ch-groups),
// block 256 = 4 rows x 64 px. Thread = one low-res px: all 100 weights in
// VGPRs (4-way s-sharing of the X window), 16 ch x (25 direct Xp loads +
// 100 FMA + two float2 stores). Plain launch bounds: wv[100]+xv[25] must
// NOT spill (needs ~140 VGPR; (256,2) would cap at 128 and spill).
__global__ __launch_bounds__(256) void k3_carafe(
    const float* __restrict__ Xp, const float* __restrict__ wn,
    float* __restrict__ out)
{
    int tid = threadIdx.x;
    int bx = blockIdx.x;
    int bb = bx >> 4;
    int rg = bx & 15;
    int y = rg * 4 + (tid >> 6);
    int px = tid & 63;
    int c0 = blockIdx.y * 16;

    float wv[100];
    const float* wsrc = wn + ((size_t)bb * 100) * NPX + y * 64 + px;
    #pragma unroll
    for (int j = 0; j < 100; ++j)
        wv[j] = wsrc[(size_t)j * NPX];

    const float* xb = Xp + ((size_t)(bb * 256 + c0) * XPP + y) * XPP + px;
    float* ob = out + ((size_t)(bb * 256 + c0) * H2 + 2 * y) * W2 + 2 * px;

    for (int ch = 0; ch < 16; ++ch) {
        const float* P = xb + (size_t)ch * (XPP * XPP);
        float xv[25];
        #pragma unroll
        for (int ki = 0; ki < 5; ++ki)
            #pragma unroll
            for (int kj = 0; kj < 5; ++kj)
                xv[ki * 5 + kj] = P[ki * XPP + kj];
        float a0 = 0.f, a1 = 0.f, a2 = 0.f, a3 = 0.f;
        #pragma unroll
        for (int k = 0; k < 25; ++k) {
            a0 += wv[k]      * xv[k];
            a1 += wv[25 + k] * xv[k];
            a2 += wv[50 + k] * xv[k];
            a3 += wv[75 + k] * xv[k];
        }
        float* o = ob + (size_t)ch * (H2 * W2);
        *(float2*)o        = make_float2(a0, a1);
        *(float2*)(o + W2) = make_float2(a2, a3);
    }
}

extern "C" void kernel_launch(void* const* d_in, const int* in_sizes, int n_in,
                              void* d_out, int out_size, void* d_ws, size_t ws_size,
                              hipStream_t stream)
{
    const float* X  = (const float*)d_in[0];
    const float* cw = (const float*)d_in[1];
    const float* cg = (const float*)d_in[2];
    const float* cb = (const float*)d_in[3];
    const float* cm = (const float*)d_in[4];
    const float* cv = (const float*)d_in[5];
    const float* ew = (const float*)d_in[6];
    const float* eg = (const float*)d_in[7];
    const float* eb = (const float*)d_in[8];
    const float* em = (const float*)d_in[9];
    const float* ev = (const float*)d_in[10];
    const float* pp = (const float*)d_in[11];
    float* out = (float*)d_out;

    float* ws   = (float*)d_ws;
    float* midp = ws;                           // 2*64*66*66  = 557,568 floats
    float* Xp   = ws + 557568;                  // 2*256*68*68 = 2,367,488 floats
    float* enc  = ws + 557568 + 2367488;        // 2*100*4096  = 819,200 floats
    float* wn   = ws + 557568 + 2367488 + 819200;

    hipMemsetAsync(ws, 0, (557568 + 2367488) * sizeof(float), stream);
    k1_conv1x1<<<dim3(64, 8), 256, 0, stream>>>(X, cw, cg, cb, cm, cv, midp, Xp);
    k2a_conv3x3<<<dim3(64, 10), 256, 0, stream>>>(midp, ew, enc);
    k2b_softmax<<<dim3(512), 64, 0, stream>>>(enc, eg, eb, em, ev, pp, wn);
    k3_carafe<<<dim3(32, 16), 256, 0, stream>>>(Xp, wn, out);
}